// Round 1
// baseline (686.475 us; speedup 1.0000x reference)
//
#include <hip/hip_runtime.h>
#include <hip/hip_bf16.h>
#include <math.h>

// HebbianPlasticLayer: B=DIN=DOUT=4096, fp32 in/out.
// out = y + eta * tanh(y) * s, y = x@W.T + bias, s = (x*x/||x||)@sigmoid(alpha).T
// Strategy: cast to bf16, two m97-style MFMA GEMMs (128x128 tile, BK=32,
// global_load_lds width=16). d_out doubles as the y_slow scratch buffer.

typedef __attribute__((ext_vector_type(4))) float floatx4;
typedef __attribute__((ext_vector_type(8))) short shortx8;

#define MAT_N 4096
#define MAT_ELEMS ((size_t)MAT_N * MAT_N)

__device__ __forceinline__ unsigned short f2bf(float f) {
    unsigned int u = __float_as_uint(f);
    unsigned int r = (u + 0x7fffu + ((u >> 16) & 1u)) >> 16;   // RNE
    return (unsigned short)r;
}

__device__ __forceinline__ void gload_lds16(const unsigned short* gptr, unsigned short* lptr) {
    __builtin_amdgcn_global_load_lds(
        (const __attribute__((address_space(1))) unsigned int*)gptr,
        (__attribute__((address_space(3))) unsigned int*)lptr,
        16, 0, 0);
}

// ---------------- row norms ----------------
__global__ __launch_bounds__(256) void row_norm_kernel(const float* __restrict__ x,
                                                       float* __restrict__ norms) {
    const int row = blockIdx.x;
    const float4* xr = (const float4*)(x + (size_t)row * MAT_N);
    float s = 0.f;
    for (int i = threadIdx.x; i < MAT_N / 4; i += 256) {
        float4 v = xr[i];
        s += v.x * v.x + v.y * v.y + v.z * v.z + v.w * v.w;
    }
    for (int off = 32; off > 0; off >>= 1) s += __shfl_down(s, off, 64);
    __shared__ float red[4];
    int lane = threadIdx.x & 63, wv = threadIdx.x >> 6;
    if (lane == 0) red[wv] = s;
    __syncthreads();
    if (threadIdx.x == 0) {
        norms[row] = sqrtf(red[0] + red[1] + red[2] + red[3]);
    }
}

// ---------------- convert x -> xb (bf16), pb = bf16(x*x/(norm+1e-8)) ----------------
__global__ __launch_bounds__(256) void conv_x_kernel(const float* __restrict__ x,
                                                     const float* __restrict__ norms,
                                                     unsigned short* __restrict__ xb,
                                                     unsigned short* __restrict__ pb) {
    size_t base = ((size_t)blockIdx.x * 256 + threadIdx.x) * 8;
    int row = (int)(base >> 12);   // 4096 elems per row; 8-groups never cross rows
    float inv = 1.0f / (norms[row] + 1e-8f);
    const float4* xp = (const float4*)(x + base);
    float4 a = xp[0], b = xp[1];
    float v[8] = {a.x, a.y, a.z, a.w, b.x, b.y, b.z, b.w};
    shortx8 xo, po;
#pragma unroll
    for (int j = 0; j < 8; j++) {
        xo[j] = (short)f2bf(v[j]);
        po[j] = (short)f2bf(v[j] * v[j] * inv);
    }
    *(shortx8*)(xb + base) = xo;
    *(shortx8*)(pb + base) = po;
}

// ---------------- convert W -> wb, ab = bf16(sigmoid(alpha)) ----------------
__global__ __launch_bounds__(256) void conv_wa_kernel(const float* __restrict__ W,
                                                      const float* __restrict__ alpha,
                                                      unsigned short* __restrict__ wb,
                                                      unsigned short* __restrict__ ab) {
    size_t base = ((size_t)blockIdx.x * 256 + threadIdx.x) * 8;
    const float4* wp = (const float4*)(W + base);
    const float4* ap = (const float4*)(alpha + base);
    float4 w0 = wp[0], w1 = wp[1], a0 = ap[0], a1 = ap[1];
    float wv[8] = {w0.x, w0.y, w0.z, w0.w, w1.x, w1.y, w1.z, w1.w};
    float av[8] = {a0.x, a0.y, a0.z, a0.w, a1.x, a1.y, a1.z, a1.w};
    shortx8 wo, ao;
#pragma unroll
    for (int j = 0; j < 8; j++) {
        wo[j] = (short)f2bf(wv[j]);
        ao[j] = (short)f2bf(1.0f / (1.0f + expf(-av[j])));
    }
    *(shortx8*)(wb + base) = wo;
    *(shortx8*)(ab + base) = ao;
}

// ---------------- GEMM: C(128x128 tile) = A(M,K) * Bm(N,K)^T, bf16->fp32 ----------------
// mode 0: out = acc + bias[col]              (y_slow)
// mode 1: y = yslow[idx]; out = y + eta*tanh(y)*acc
__global__ __launch_bounds__(256) void gemm_bt_kernel(
    const unsigned short* __restrict__ A,
    const unsigned short* __restrict__ Bm,
    const float* __restrict__ bias,
    const float* yslow,
    const float* __restrict__ eta_p,
    float* out,
    int mode) {
    constexpr int K = MAT_N;
    constexpr int N = MAT_N;
    __shared__ __align__(16) unsigned short sA[128 * 32];
    __shared__ __align__(16) unsigned short sB[128 * 32];

    const int tid = threadIdx.x;
    const int row0 = blockIdx.y * 128;
    const int col0 = blockIdx.x * 128;
    const int lane = tid & 63;
    const int wave = tid >> 6;
    const int wm = (wave >> 1) * 64;   // 2x2 waves, each 64x64
    const int wn = (wave & 1) * 64;
    const int quad = lane >> 4;
    const int l16 = lane & 15;

    floatx4 acc[4][4];
#pragma unroll
    for (int i = 0; i < 4; i++)
#pragma unroll
        for (int j = 0; j < 4; j++) acc[i][j] = (floatx4){0.f, 0.f, 0.f, 0.f};

    // staging: thread t loads 8 bf16 = 16B; 256 threads cover 64 rows x 32 cols per issue
    const unsigned short* aptr = A + (size_t)(row0 + (tid >> 2)) * K + (tid & 3) * 8;
    const unsigned short* bptr = Bm + (size_t)(col0 + (tid >> 2)) * K + (tid & 3) * 8;
    unsigned short* sA_st = sA + tid * 8;   // byte offset tid*16: wave-uniform base + lane*16
    unsigned short* sB_st = sB + tid * 8;

    for (int k0 = 0; k0 < K; k0 += 32) {
        gload_lds16(aptr + k0, sA_st);
        gload_lds16(aptr + k0 + (size_t)64 * K, sA_st + 64 * 32);
        gload_lds16(bptr + k0, sB_st);
        gload_lds16(bptr + k0 + (size_t)64 * K, sB_st + 64 * 32);
        __syncthreads();   // drains vmcnt before barrier -> staged data visible

        shortx8 af[4], bfr[4];
#pragma unroll
        for (int i = 0; i < 4; i++)
            af[i] = *(const shortx8*)(sA + (wm + i * 16 + l16) * 32 + quad * 8);
#pragma unroll
        for (int j = 0; j < 4; j++)
            bfr[j] = *(const shortx8*)(sB + (wn + j * 16 + l16) * 32 + quad * 8);
#pragma unroll
        for (int i = 0; i < 4; i++)
#pragma unroll
            for (int j = 0; j < 4; j++)
                acc[i][j] = __builtin_amdgcn_mfma_f32_16x16x32_bf16(af[i], bfr[j], acc[i][j], 0, 0, 0);
        __syncthreads();
    }

    const float eta = (mode == 1) ? *eta_p : 0.f;
#pragma unroll
    for (int i = 0; i < 4; i++) {
#pragma unroll
        for (int j = 0; j < 4; j++) {
#pragma unroll
            for (int r = 0; r < 4; r++) {
                // C/D layout: row = quad*4 + r, col = lane&15   [m89/m91 verified]
                int grow = row0 + wm + i * 16 + quad * 4 + r;
                int gcol = col0 + wn + j * 16 + l16;
                size_t idx = (size_t)grow * N + gcol;
                float v = acc[i][j][r];
                if (mode == 0) {
                    out[idx] = v + bias[gcol];
                } else {
                    float y = yslow[idx];
                    out[idx] = y + eta * tanhf(y) * v;
                }
            }
        }
    }
}

extern "C" void kernel_launch(void* const* d_in, const int* in_sizes, int n_in,
                              void* d_out, int out_size, void* d_ws, size_t ws_size,
                              hipStream_t stream) {
    const float* x     = (const float*)d_in[0];
    const float* W     = (const float*)d_in[1];
    const float* alpha = (const float*)d_in[2];
    const float* eta   = (const float*)d_in[3];
    const float* bias  = (const float*)d_in[4];
    float* out = (float*)d_out;

    // workspace layout: norms (16KB) | xb | pb | wb | ab  (4x32MB bf16) = ~128MB
    char* ws = (char*)d_ws;
    float* norms = (float*)ws;
    unsigned short* xb = (unsigned short*)(ws + 16384);
    unsigned short* pb = xb + MAT_ELEMS;
    unsigned short* wb = pb + MAT_ELEMS;
    unsigned short* ab = wb + MAT_ELEMS;

    row_norm_kernel<<<MAT_N, 256, 0, stream>>>(x, norms);
    conv_x_kernel<<<MAT_ELEMS / (8 * 256), 256, 0, stream>>>(x, norms, xb, pb);
    conv_wa_kernel<<<MAT_ELEMS / (8 * 256), 256, 0, stream>>>(W, alpha, wb, ab);

    dim3 grid(MAT_N / 128, MAT_N / 128);
    // GEMM1: d_out <- x@W.T + bias  (d_out doubles as y_slow scratch)
    gemm_bt_kernel<<<grid, 256, 0, stream>>>(xb, wb, bias, nullptr, nullptr, out, 0);
    // GEMM2: d_out <- y + eta*tanh(y)*s
    gemm_bt_kernel<<<grid, 256, 0, stream>>>(pb, ab, nullptr, out, eta, out, 1);
}

// Round 2
// 586.793 us; speedup vs baseline: 1.1699x; 1.1699x over previous
//
#include <hip/hip_runtime.h>
#include <hip/hip_bf16.h>
#include <math.h>

// HebbianPlasticLayer: B=DIN=DOUT=4096, fp32 in/out.
// out = y + eta*tanh(y)*s,  y = x@W.T + bias,  s = (x*x/||x||)@sigmoid(alpha).T
// Round 2: FUSED dual-GEMM (both share the same tile grid & K loop) —
// 32 MFMAs per barrier pair instead of 16, no y_slow round-trip.

typedef __attribute__((ext_vector_type(4))) float floatx4;
typedef __attribute__((ext_vector_type(8))) short shortx8;

#define MAT_N 4096
#define MAT_ELEMS ((size_t)MAT_N * MAT_N)

__device__ __forceinline__ unsigned short f2bf(float f) {
    unsigned int u = __float_as_uint(f);
    unsigned int r = (u + 0x7fffu + ((u >> 16) & 1u)) >> 16;   // RNE
    return (unsigned short)r;
}

__device__ __forceinline__ void gload_lds16(const unsigned short* gptr, unsigned short* lptr) {
    __builtin_amdgcn_global_load_lds(
        (const __attribute__((address_space(1))) unsigned int*)gptr,
        (__attribute__((address_space(3))) unsigned int*)lptr,
        16, 0, 0);
}

// ---------- fused row-norm + convert: xb = bf16(x), pb = bf16(x*x/(||x||+1e-8)) ----------
// one block per row; x read exactly once (16 floats/thread held in registers)
__global__ __launch_bounds__(256) void normconv_x_kernel(const float* __restrict__ x,
                                                         unsigned short* __restrict__ xb,
                                                         unsigned short* __restrict__ pb) {
    const int row = blockIdx.x;
    const float4* xr = (const float4*)(x + (size_t)row * MAT_N);
    float4 v[4];
    float s = 0.f;
#pragma unroll
    for (int i = 0; i < 4; i++) {
        v[i] = xr[threadIdx.x + i * 256];
        s += v[i].x * v[i].x + v[i].y * v[i].y + v[i].z * v[i].z + v[i].w * v[i].w;
    }
    for (int off = 32; off > 0; off >>= 1) s += __shfl_down(s, off, 64);
    __shared__ float red[4];
    if ((threadIdx.x & 63) == 0) red[threadIdx.x >> 6] = s;
    __syncthreads();
    const float inv = 1.0f / (sqrtf(red[0] + red[1] + red[2] + red[3]) + 1e-8f);
    unsigned short* xrow = xb + (size_t)row * MAT_N;
    unsigned short* prow = pb + (size_t)row * MAT_N;
#pragma unroll
    for (int i = 0; i < 4; i++) {
        float e[4] = {v[i].x, v[i].y, v[i].z, v[i].w};
        ushort4 xo, po;
        xo.x = f2bf(e[0]); xo.y = f2bf(e[1]); xo.z = f2bf(e[2]); xo.w = f2bf(e[3]);
        po.x = f2bf(e[0] * e[0] * inv); po.y = f2bf(e[1] * e[1] * inv);
        po.z = f2bf(e[2] * e[2] * inv); po.w = f2bf(e[3] * e[3] * inv);
        *(ushort4*)(xrow + (threadIdx.x + i * 256) * 4) = xo;
        *(ushort4*)(prow + (threadIdx.x + i * 256) * 4) = po;
    }
}

// ---------- convert W -> wb, ab = bf16(sigmoid(alpha)) ----------
__global__ __launch_bounds__(256) void conv_wa_kernel(const float* __restrict__ W,
                                                      const float* __restrict__ alpha,
                                                      unsigned short* __restrict__ wb,
                                                      unsigned short* __restrict__ ab) {
    size_t base = ((size_t)blockIdx.x * 256 + threadIdx.x) * 8;
    const float4* wp = (const float4*)(W + base);
    const float4* ap = (const float4*)(alpha + base);
    float4 w0 = wp[0], w1 = wp[1], a0 = ap[0], a1 = ap[1];
    float wv[8] = {w0.x, w0.y, w0.z, w0.w, w1.x, w1.y, w1.z, w1.w};
    float av[8] = {a0.x, a0.y, a0.z, a0.w, a1.x, a1.y, a1.z, a1.w};
    shortx8 wo, ao;
#pragma unroll
    for (int j = 0; j < 8; j++) {
        wo[j] = (short)f2bf(wv[j]);
        ao[j] = (short)f2bf(1.0f / (1.0f + __expf(-av[j])));
    }
    *(shortx8*)(wb + base) = wo;
    *(shortx8*)(ab + base) = ao;
}

// ---------- fused dual-GEMM: accY = X@Wb.T, accS = P@Ab.T, epilogue combines ----------
__global__ __launch_bounds__(256, 2) void fused_gemm_kernel(
    const unsigned short* __restrict__ X,
    const unsigned short* __restrict__ Wb,
    const unsigned short* __restrict__ P,
    const unsigned short* __restrict__ Ab,
    const float* __restrict__ bias,
    const float* __restrict__ eta_p,
    float* __restrict__ out) {
    constexpr int K = MAT_N;
    constexpr int N = MAT_N;
    __shared__ __align__(16) unsigned short sX[128 * 32];
    __shared__ __align__(16) unsigned short sW[128 * 32];
    __shared__ __align__(16) unsigned short sP[128 * 32];
    __shared__ __align__(16) unsigned short sA[128 * 32];

    const int tid = threadIdx.x;
    const int row0 = blockIdx.y * 128;
    const int col0 = blockIdx.x * 128;
    const int lane = tid & 63;
    const int wave = tid >> 6;
    const int wm = (wave >> 1) * 64;   // 2x2 waves, 64x64 each
    const int wn = (wave & 1) * 64;
    const int quad = lane >> 4;
    const int l16 = lane & 15;

    floatx4 accY[4][4], accS[4][4];
#pragma unroll
    for (int i = 0; i < 4; i++)
#pragma unroll
        for (int j = 0; j < 4; j++) {
            accY[i][j] = (floatx4){0.f, 0.f, 0.f, 0.f};
            accS[i][j] = (floatx4){0.f, 0.f, 0.f, 0.f};
        }

    // staging: thread t -> 16B; 256 threads cover 64 rows x 32 cols per issue
    const size_t ga = (size_t)(row0 + (tid >> 2)) * K + (tid & 3) * 8;
    const size_t gb = (size_t)(col0 + (tid >> 2)) * K + (tid & 3) * 8;
    const size_t half = (size_t)64 * K;
    unsigned short* sX_st = sX + tid * 8;
    unsigned short* sW_st = sW + tid * 8;
    unsigned short* sP_st = sP + tid * 8;
    unsigned short* sA_st = sA + tid * 8;

    for (int k0 = 0; k0 < K; k0 += 32) {
        gload_lds16(X + ga + k0, sX_st);
        gload_lds16(X + ga + half + k0, sX_st + 64 * 32);
        gload_lds16(Wb + gb + k0, sW_st);
        gload_lds16(Wb + gb + half + k0, sW_st + 64 * 32);
        gload_lds16(P + ga + k0, sP_st);
        gload_lds16(P + ga + half + k0, sP_st + 64 * 32);
        gload_lds16(Ab + gb + k0, sA_st);
        gload_lds16(Ab + gb + half + k0, sA_st + 64 * 32);
        __syncthreads();   // single vmcnt(0) drain covers all 8 staged loads

        {
            shortx8 af[4], bfr[4];
#pragma unroll
            for (int i = 0; i < 4; i++)
                af[i] = *(const shortx8*)(sX + (wm + i * 16 + l16) * 32 + quad * 8);
#pragma unroll
            for (int j = 0; j < 4; j++)
                bfr[j] = *(const shortx8*)(sW + (wn + j * 16 + l16) * 32 + quad * 8);
#pragma unroll
            for (int i = 0; i < 4; i++)
#pragma unroll
                for (int j = 0; j < 4; j++)
                    accY[i][j] = __builtin_amdgcn_mfma_f32_16x16x32_bf16(af[i], bfr[j], accY[i][j], 0, 0, 0);
        }
        {
            shortx8 af[4], bfr[4];
#pragma unroll
            for (int i = 0; i < 4; i++)
                af[i] = *(const shortx8*)(sP + (wm + i * 16 + l16) * 32 + quad * 8);
#pragma unroll
            for (int j = 0; j < 4; j++)
                bfr[j] = *(const shortx8*)(sA + (wn + j * 16 + l16) * 32 + quad * 8);
#pragma unroll
            for (int i = 0; i < 4; i++)
#pragma unroll
                for (int j = 0; j < 4; j++)
                    accS[i][j] = __builtin_amdgcn_mfma_f32_16x16x32_bf16(af[i], bfr[j], accS[i][j], 0, 0, 0);
        }
        __syncthreads();
    }

    const float eta = *eta_p;
#pragma unroll
    for (int i = 0; i < 4; i++) {
#pragma unroll
        for (int j = 0; j < 4; j++) {
#pragma unroll
            for (int r = 0; r < 4; r++) {
                // C/D layout: row = quad*4 + r, col = lane&15   [m89/m91 verified]
                int grow = row0 + wm + i * 16 + quad * 4 + r;
                int gcol = col0 + wn + j * 16 + l16;
                float y = accY[i][j][r] + bias[gcol];
                float s = accS[i][j][r];
                out[(size_t)grow * N + gcol] = y + eta * tanhf(y) * s;
            }
        }
    }
}

extern "C" void kernel_launch(void* const* d_in, const int* in_sizes, int n_in,
                              void* d_out, int out_size, void* d_ws, size_t ws_size,
                              hipStream_t stream) {
    const float* x     = (const float*)d_in[0];
    const float* W     = (const float*)d_in[1];
    const float* alpha = (const float*)d_in[2];
    const float* eta   = (const float*)d_in[3];
    const float* bias  = (const float*)d_in[4];
    float* out = (float*)d_out;

    // workspace layout: xb | pb | wb | ab  (4x32MB bf16) = 128MB
    unsigned short* xb = (unsigned short*)d_ws;
    unsigned short* pb = xb + MAT_ELEMS;
    unsigned short* wb = pb + MAT_ELEMS;
    unsigned short* ab = wb + MAT_ELEMS;

    normconv_x_kernel<<<MAT_N, 256, 0, stream>>>(x, xb, pb);
    conv_wa_kernel<<<MAT_ELEMS / (8 * 256), 256, 0, stream>>>(W, alpha, wb, ab);

    dim3 grid(MAT_N / 128, MAT_N / 128);
    fused_gemm_kernel<<<grid, 256, 0, stream>>>(xb, wb, pb, ab, bias, eta, out);
}

// Round 3
// 542.696 us; speedup vs baseline: 1.2649x; 1.0813x over previous
//
#include <hip/hip_runtime.h>
#include <hip/hip_bf16.h>
#include <math.h>

// HebbianPlasticLayer: B=DIN=DOUT=4096, fp32 in/out.
// out = y + eta*tanh(y)*s,  y = x@W.T + bias,  s = (x*x/||x||)@sigmoid(alpha).T
// Round 3: fused dual-GEMM, BK=64 (64 MFMAs per barrier pair, halved barrier
// count vs R2) + XOR-swizzled LDS (kc ^= row&7 on 16B chunks) so ds_read_b128
// fragment reads are bank-conflict-free with the 128B row stride.
// Occupancy stays 2 blocks/CU (VGPR-limited anyway; LDS = 64KB).

typedef __attribute__((ext_vector_type(4))) float floatx4;
typedef __attribute__((ext_vector_type(8))) short shortx8;

#define MAT_N 4096
#define MAT_ELEMS ((size_t)MAT_N * MAT_N)

__device__ __forceinline__ unsigned short f2bf(float f) {
    unsigned int u = __float_as_uint(f);
    unsigned int r = (u + 0x7fffu + ((u >> 16) & 1u)) >> 16;   // RNE
    return (unsigned short)r;
}

__device__ __forceinline__ void gload_lds16(const unsigned short* gptr, unsigned short* lptr) {
    __builtin_amdgcn_global_load_lds(
        (const __attribute__((address_space(1))) unsigned int*)gptr,
        (__attribute__((address_space(3))) unsigned int*)lptr,
        16, 0, 0);
}

// ---------- fused row-norm + convert: xb = bf16(x), pb = bf16(x*x/(||x||+1e-8)) ----------
__global__ __launch_bounds__(256) void normconv_x_kernel(const float* __restrict__ x,
                                                         unsigned short* __restrict__ xb,
                                                         unsigned short* __restrict__ pb) {
    const int row = blockIdx.x;
    const float4* xr = (const float4*)(x + (size_t)row * MAT_N);
    float4 v[4];
    float s = 0.f;
#pragma unroll
    for (int i = 0; i < 4; i++) {
        v[i] = xr[threadIdx.x + i * 256];
        s += v[i].x * v[i].x + v[i].y * v[i].y + v[i].z * v[i].z + v[i].w * v[i].w;
    }
    for (int off = 32; off > 0; off >>= 1) s += __shfl_down(s, off, 64);
    __shared__ float red[4];
    if ((threadIdx.x & 63) == 0) red[threadIdx.x >> 6] = s;
    __syncthreads();
    const float inv = 1.0f / (sqrtf(red[0] + red[1] + red[2] + red[3]) + 1e-8f);
    unsigned short* xrow = xb + (size_t)row * MAT_N;
    unsigned short* prow = pb + (size_t)row * MAT_N;
#pragma unroll
    for (int i = 0; i < 4; i++) {
        float e[4] = {v[i].x, v[i].y, v[i].z, v[i].w};
        ushort4 xo, po;
        xo.x = f2bf(e[0]); xo.y = f2bf(e[1]); xo.z = f2bf(e[2]); xo.w = f2bf(e[3]);
        po.x = f2bf(e[0] * e[0] * inv); po.y = f2bf(e[1] * e[1] * inv);
        po.z = f2bf(e[2] * e[2] * inv); po.w = f2bf(e[3] * e[3] * inv);
        *(ushort4*)(xrow + (threadIdx.x + i * 256) * 4) = xo;
        *(ushort4*)(prow + (threadIdx.x + i * 256) * 4) = po;
    }
}

// ---------- convert W -> wb, ab = bf16(sigmoid(alpha)) ----------
__global__ __launch_bounds__(256) void conv_wa_kernel(const float* __restrict__ W,
                                                      const float* __restrict__ alpha,
                                                      unsigned short* __restrict__ wb,
                                                      unsigned short* __restrict__ ab) {
    size_t base = ((size_t)blockIdx.x * 256 + threadIdx.x) * 8;
    const float4* wp = (const float4*)(W + base);
    const float4* ap = (const float4*)(alpha + base);
    float4 w0 = wp[0], w1 = wp[1], a0 = ap[0], a1 = ap[1];
    float wv[8] = {w0.x, w0.y, w0.z, w0.w, w1.x, w1.y, w1.z, w1.w};
    float av[8] = {a0.x, a0.y, a0.z, a0.w, a1.x, a1.y, a1.z, a1.w};
    shortx8 wo, ao;
#pragma unroll
    for (int j = 0; j < 8; j++) {
        wo[j] = (short)f2bf(wv[j]);
        ao[j] = (short)f2bf(1.0f / (1.0f + __expf(-av[j])));
    }
    *(shortx8*)(wb + base) = wo;
    *(shortx8*)(ab + base) = ao;
}

// ---------- fused dual-GEMM, BK=64, swizzled LDS ----------
// LDS stream layout: [row 0..127][kc' 0..7] of 16B chunks, row stride 128B.
// Chunk for global (row, kc) lives at kc' = kc ^ (row & 7).  Staging thread t
// (issue i): row = i*32 + (t>>3), slot = t&7, fetches global kc = slot^(row&7);
// since i*32 % 8 == 0, the fetched kc is issue-invariant.
__global__ __launch_bounds__(256, 2) void fused_gemm_kernel(
    const unsigned short* __restrict__ X,
    const unsigned short* __restrict__ Wb,
    const unsigned short* __restrict__ P,
    const unsigned short* __restrict__ Ab,
    const float* __restrict__ bias,
    const float* __restrict__ eta_p,
    float* __restrict__ out) {
    constexpr int K = MAT_N;
    constexpr int N = MAT_N;
    constexpr int BK = 64;                       // shorts per row per K-step
    __shared__ __align__(16) unsigned short sX[128 * BK];
    __shared__ __align__(16) unsigned short sW[128 * BK];
    __shared__ __align__(16) unsigned short sP[128 * BK];
    __shared__ __align__(16) unsigned short sA[128 * BK];

    const int tid = threadIdx.x;
    const int row0 = blockIdx.y * 128;
    const int col0 = blockIdx.x * 128;
    const int lane = tid & 63;
    const int wave = tid >> 6;
    const int wm = (wave >> 1) * 64;   // 2x2 waves, 64x64 each
    const int wn = (wave & 1) * 64;
    const int quad = lane >> 4;
    const int l16 = lane & 15;

    floatx4 accY[4][4], accS[4][4];
#pragma unroll
    for (int i = 0; i < 4; i++)
#pragma unroll
        for (int j = 0; j < 4; j++) {
            accY[i][j] = (floatx4){0.f, 0.f, 0.f, 0.f};
            accS[i][j] = (floatx4){0.f, 0.f, 0.f, 0.f};
        }

    // --- staging addresses ---
    const int row_s = tid >> 3;                        // 0..31
    const int kc_g  = (tid & 7) ^ (row_s & 7);         // global chunk this thread fetches
    const size_t arow = (size_t)(row0 + row_s) * K + kc_g * 8;
    const size_t brow = (size_t)(col0 + row_s) * K + kc_g * 8;

    // --- fragment read offsets (shorts). row&7 == l16&7 for all frag rows. ---
    const int kcp0 = ((0 * 4 + quad) ^ (l16 & 7)) * 8;   // sub-step s=0
    const int kcp1 = ((1 * 4 + quad) ^ (l16 & 7)) * 8;   // sub-step s=1

    for (int k0 = 0; k0 < K; k0 += BK) {
#pragma unroll
        for (int i = 0; i < 4; i++) {
            const size_t go = (size_t)i * 32 * K + k0;
            unsigned short* ls = (unsigned short*)0 + i * 2048 + tid * 8;
            gload_lds16(X + arow + go, sX + (i * 2048 + tid * 8));
            gload_lds16(Wb + brow + go, sW + (i * 2048 + tid * 8));
            gload_lds16(P + arow + go, sP + (i * 2048 + tid * 8));
            gload_lds16(Ab + brow + go, sA + (i * 2048 + tid * 8));
            (void)ls;
        }
        __syncthreads();   // single vmcnt(0) drain covers all 16 staged loads

#pragma unroll
        for (int s = 0; s < 2; s++) {
            const int kcp = (s == 0) ? kcp0 : kcp1;
            {
                shortx8 af[4], bfr[4];
#pragma unroll
                for (int i = 0; i < 4; i++)
                    af[i] = *(const shortx8*)(sX + (wm + i * 16 + l16) * BK + kcp);
#pragma unroll
                for (int j = 0; j < 4; j++)
                    bfr[j] = *(const shortx8*)(sW + (wn + j * 16 + l16) * BK + kcp);
#pragma unroll
                for (int i = 0; i < 4; i++)
#pragma unroll
                    for (int j = 0; j < 4; j++)
                        accY[i][j] = __builtin_amdgcn_mfma_f32_16x16x32_bf16(af[i], bfr[j], accY[i][j], 0, 0, 0);
            }
            {
                shortx8 af[4], bfr[4];
#pragma unroll
                for (int i = 0; i < 4; i++)
                    af[i] = *(const shortx8*)(sP + (wm + i * 16 + l16) * BK + kcp);
#pragma unroll
                for (int j = 0; j < 4; j++)
                    bfr[j] = *(const shortx8*)(sA + (wn + j * 16 + l16) * BK + kcp);
#pragma unroll
                for (int i = 0; i < 4; i++)
#pragma unroll
                    for (int j = 0; j < 4; j++)
                        accS[i][j] = __builtin_amdgcn_mfma_f32_16x16x32_bf16(af[i], bfr[j], accS[i][j], 0, 0, 0);
            }
        }
        __syncthreads();
    }

    const float eta = *eta_p;
#pragma unroll
    for (int i = 0; i < 4; i++) {
#pragma unroll
        for (int j = 0; j < 4; j++) {
#pragma unroll
            for (int r = 0; r < 4; r++) {
                // C/D layout: row = quad*4 + r, col = lane&15   [m89/m91 verified]
                int grow = row0 + wm + i * 16 + quad * 4 + r;
                int gcol = col0 + wn + j * 16 + l16;
                float y = accY[i][j][r] + bias[gcol];
                float s = accS[i][j][r];
                out[(size_t)grow * N + gcol] = y + eta * tanhf(y) * s;
            }
        }
    }
}

extern "C" void kernel_launch(void* const* d_in, const int* in_sizes, int n_in,
                              void* d_out, int out_size, void* d_ws, size_t ws_size,
                              hipStream_t stream) {
    const float* x     = (const float*)d_in[0];
    const float* W     = (const float*)d_in[1];
    const float* alpha = (const float*)d_in[2];
    const float* eta   = (const float*)d_in[3];
    const float* bias  = (const float*)d_in[4];
    float* out = (float*)d_out;

    // workspace layout: xb | pb | wb | ab  (4x32MB bf16) = 128MB
    unsigned short* xb = (unsigned short*)d_ws;
    unsigned short* pb = xb + MAT_ELEMS;
    unsigned short* wb = pb + MAT_ELEMS;
    unsigned short* ab = wb + MAT_ELEMS;

    normconv_x_kernel<<<MAT_N, 256, 0, stream>>>(x, xb, pb);
    conv_wa_kernel<<<MAT_ELEMS / (8 * 256), 256, 0, stream>>>(W, alpha, wb, ab);

    dim3 grid(MAT_N / 128, MAT_N / 128);
    fused_gemm_kernel<<<grid, 256, 0, stream>>>(xb, wb, pb, ab, bias, eta, out);
}

// Round 4
// 513.364 us; speedup vs baseline: 1.3372x; 1.0571x over previous
//
#include <hip/hip_runtime.h>
#include <hip/hip_bf16.h>
#include <math.h>

// HebbianPlasticLayer: B=DIN=DOUT=4096, fp32 in/out.
// out = y + eta*tanh(y)*s,  y = x@W.T + bias,  s = (x*x/||x||)@sigmoid(alpha).T
// Round 4: 512-thread blocks (8 waves, 4x2), per-wave tile 32x64 per GEMM ->
// acc halves to 64 regs/lane, __launch_bounds__(512,4) caps regs at 128 ->
// 4 waves/SIMD (16 waves/CU) to hide the vmcnt(0) barrier drain.
// BK=64 + XOR-swizzled LDS (R3: zero bank conflicts) retained.

typedef __attribute__((ext_vector_type(4))) float floatx4;
typedef __attribute__((ext_vector_type(8))) short shortx8;

#define MAT_N 4096
#define MAT_ELEMS ((size_t)MAT_N * MAT_N)

__device__ __forceinline__ unsigned short f2bf(float f) {
    unsigned int u = __float_as_uint(f);
    unsigned int r = (u + 0x7fffu + ((u >> 16) & 1u)) >> 16;   // RNE
    return (unsigned short)r;
}

__device__ __forceinline__ void gload_lds16(const unsigned short* gptr, unsigned short* lptr) {
    __builtin_amdgcn_global_load_lds(
        (const __attribute__((address_space(1))) unsigned int*)gptr,
        (__attribute__((address_space(3))) unsigned int*)lptr,
        16, 0, 0);
}

// ---------- merged conversion kernel ----------
// blocks [0,4096):    row-norm + convert x -> xb, pb
// blocks [4096,12288): convert W -> wb, sigmoid(alpha) -> ab
__global__ __launch_bounds__(256) void conv_all_kernel(const float* __restrict__ x,
                                                       const float* __restrict__ W,
                                                       const float* __restrict__ alpha,
                                                       unsigned short* __restrict__ xb,
                                                       unsigned short* __restrict__ pb,
                                                       unsigned short* __restrict__ wb,
                                                       unsigned short* __restrict__ ab) {
    if (blockIdx.x < MAT_N) {
        const int row = blockIdx.x;
        const float4* xr = (const float4*)(x + (size_t)row * MAT_N);
        float4 v[4];
        float s = 0.f;
#pragma unroll
        for (int i = 0; i < 4; i++) {
            v[i] = xr[threadIdx.x + i * 256];
            s += v[i].x * v[i].x + v[i].y * v[i].y + v[i].z * v[i].z + v[i].w * v[i].w;
        }
        for (int off = 32; off > 0; off >>= 1) s += __shfl_down(s, off, 64);
        __shared__ float red[4];
        if ((threadIdx.x & 63) == 0) red[threadIdx.x >> 6] = s;
        __syncthreads();
        const float inv = 1.0f / (sqrtf(red[0] + red[1] + red[2] + red[3]) + 1e-8f);
        unsigned short* xrow = xb + (size_t)row * MAT_N;
        unsigned short* prow = pb + (size_t)row * MAT_N;
#pragma unroll
        for (int i = 0; i < 4; i++) {
            float e[4] = {v[i].x, v[i].y, v[i].z, v[i].w};
            ushort4 xo, po;
            xo.x = f2bf(e[0]); xo.y = f2bf(e[1]); xo.z = f2bf(e[2]); xo.w = f2bf(e[3]);
            po.x = f2bf(e[0] * e[0] * inv); po.y = f2bf(e[1] * e[1] * inv);
            po.z = f2bf(e[2] * e[2] * inv); po.w = f2bf(e[3] * e[3] * inv);
            *(ushort4*)(xrow + (threadIdx.x + i * 256) * 4) = xo;
            *(ushort4*)(prow + (threadIdx.x + i * 256) * 4) = po;
        }
    } else {
        size_t base = ((size_t)(blockIdx.x - MAT_N) * 256 + threadIdx.x) * 8;
        const float4* wp = (const float4*)(W + base);
        const float4* ap = (const float4*)(alpha + base);
        float4 w0 = wp[0], w1 = wp[1], a0 = ap[0], a1 = ap[1];
        float wv[8] = {w0.x, w0.y, w0.z, w0.w, w1.x, w1.y, w1.z, w1.w};
        float av[8] = {a0.x, a0.y, a0.z, a0.w, a1.x, a1.y, a1.z, a1.w};
        shortx8 wo, ao;
#pragma unroll
        for (int j = 0; j < 8; j++) {
            wo[j] = (short)f2bf(wv[j]);
            ao[j] = (short)f2bf(1.0f / (1.0f + __expf(-av[j])));
        }
        *(shortx8*)(wb + base) = wo;
        *(shortx8*)(ab + base) = ao;
    }
}

// ---------- fused dual-GEMM, 512 threads, BK=64, swizzled LDS ----------
// LDS layout per buffer: [row 0..127][kc' 0..7] 16B chunks, row stride 128B;
// chunk (row,kc) stored at kc' = kc ^ (row&7).
// Staging: thread t -> row_s = t>>3 (0..63), slot = t&7, global kc = slot^(row_s&7);
// LDS dest = i*4096 + t*8 shorts  (== wave-uniform base + lane*16B).  i adds 64 rows.
__global__ __launch_bounds__(512, 4) void fused_gemm_kernel(
    const unsigned short* __restrict__ X,
    const unsigned short* __restrict__ Wb,
    const unsigned short* __restrict__ P,
    const unsigned short* __restrict__ Ab,
    const float* __restrict__ bias,
    const float* __restrict__ eta_p,
    float* __restrict__ out) {
    constexpr int K = MAT_N;
    constexpr int N = MAT_N;
    constexpr int BK = 64;                       // shorts per row per K-step
    __shared__ __align__(16) unsigned short sX[128 * BK];
    __shared__ __align__(16) unsigned short sW[128 * BK];
    __shared__ __align__(16) unsigned short sP[128 * BK];
    __shared__ __align__(16) unsigned short sA[128 * BK];

    const int tid = threadIdx.x;
    const int row0 = blockIdx.y * 128;
    const int col0 = blockIdx.x * 128;
    const int lane = tid & 63;
    const int wave = tid >> 6;           // 0..7
    const int wm = (wave >> 1) * 32;     // 4x2 wave grid: 32-row x 64-col per wave
    const int wn = (wave & 1) * 64;
    const int quad = lane >> 4;
    const int l16 = lane & 15;

    floatx4 accY[2][4], accS[2][4];
#pragma unroll
    for (int i = 0; i < 2; i++)
#pragma unroll
        for (int j = 0; j < 4; j++) {
            accY[i][j] = (floatx4){0.f, 0.f, 0.f, 0.f};
            accS[i][j] = (floatx4){0.f, 0.f, 0.f, 0.f};
        }

    // staging addresses
    const int row_s = tid >> 3;                        // 0..63
    const int kc_g  = (tid & 7) ^ (row_s & 7);         // global 16B chunk
    const size_t arow = (size_t)(row0 + row_s) * K + kc_g * 8;
    const size_t brow = (size_t)(col0 + row_s) * K + kc_g * 8;

    for (int k0 = 0; k0 < K; k0 += BK) {
#pragma unroll
        for (int i = 0; i < 2; i++) {
            const size_t go = (size_t)i * 64 * K + k0;
            const int lo = i * 4096 + tid * 8;
            gload_lds16(X + arow + go, sX + lo);
            gload_lds16(Wb + brow + go, sW + lo);
            gload_lds16(P + arow + go, sP + lo);
            gload_lds16(Ab + brow + go, sA + lo);
        }
        __syncthreads();   // single vmcnt(0) drain covers all 8 staged loads

#pragma unroll
        for (int s = 0; s < 2; s++) {
            const int kcp = ((s * 4 + quad) ^ (l16 & 7)) * 8;
            {
                shortx8 af[2], bfr[4];
#pragma unroll
                for (int i = 0; i < 2; i++)
                    af[i] = *(const shortx8*)(sX + (wm + i * 16 + l16) * BK + kcp);
#pragma unroll
                for (int j = 0; j < 4; j++)
                    bfr[j] = *(const shortx8*)(sW + (wn + j * 16 + l16) * BK + kcp);
#pragma unroll
                for (int i = 0; i < 2; i++)
#pragma unroll
                    for (int j = 0; j < 4; j++)
                        accY[i][j] = __builtin_amdgcn_mfma_f32_16x16x32_bf16(af[i], bfr[j], accY[i][j], 0, 0, 0);
            }
            {
                shortx8 af[2], bfr[4];
#pragma unroll
                for (int i = 0; i < 2; i++)
                    af[i] = *(const shortx8*)(sP + (wm + i * 16 + l16) * BK + kcp);
#pragma unroll
                for (int j = 0; j < 4; j++)
                    bfr[j] = *(const shortx8*)(sA + (wn + j * 16 + l16) * BK + kcp);
#pragma unroll
                for (int i = 0; i < 2; i++)
#pragma unroll
                    for (int j = 0; j < 4; j++)
                        accS[i][j] = __builtin_amdgcn_mfma_f32_16x16x32_bf16(af[i], bfr[j], accS[i][j], 0, 0, 0);
            }
        }
        __syncthreads();
    }

    const float eta = *eta_p;
#pragma unroll
    for (int i = 0; i < 2; i++) {
#pragma unroll
        for (int j = 0; j < 4; j++) {
#pragma unroll
            for (int r = 0; r < 4; r++) {
                // C/D layout: row = quad*4 + r, col = lane&15   [m89/m91 verified]
                int grow = row0 + wm + i * 16 + quad * 4 + r;
                int gcol = col0 + wn + j * 16 + l16;
                float y = accY[i][j][r] + bias[gcol];
                float s = accS[i][j][r];
                out[(size_t)grow * N + gcol] = y + eta * tanhf(y) * s;
            }
        }
    }
}

extern "C" void kernel_launch(void* const* d_in, const int* in_sizes, int n_in,
                              void* d_out, int out_size, void* d_ws, size_t ws_size,
                              hipStream_t stream) {
    const float* x     = (const float*)d_in[0];
    const float* W     = (const float*)d_in[1];
    const float* alpha = (const float*)d_in[2];
    const float* eta   = (const float*)d_in[3];
    const float* bias  = (const float*)d_in[4];
    float* out = (float*)d_out;

    // workspace layout: xb | pb | wb | ab  (4x32MB bf16) = 128MB
    unsigned short* xb = (unsigned short*)d_ws;
    unsigned short* pb = xb + MAT_ELEMS;
    unsigned short* wb = pb + MAT_ELEMS;
    unsigned short* ab = wb + MAT_ELEMS;

    conv_all_kernel<<<MAT_N + MAT_ELEMS / (8 * 256), 256, 0, stream>>>(x, W, alpha, xb, pb, wb, ab);

    dim3 grid(MAT_N / 128, MAT_N / 128);
    fused_gemm_kernel<<<grid, 512, 0, stream>>>(xb, wb, pb, ab, bias, eta, out);
}